// Round 2
// baseline (179.605 us; speedup 1.0000x reference)
//
#include <hip/hip_runtime.h>

// --- MFMA fp16 LSTM, Round 13: group-alternating gate<->MFMA pipeline ---
// r12 (95us): 512-thr blocks, 2/CU; phase = read->MFMA->gate->write serial
// chain, all waves in lockstep -> 46% all-pipe idle (VALUBusy 54% flat).
// r13: split 32 batch into 2 groups of 16 alternating per phase:
//   phase P: group (P&1) does LDS-reads+MFMAs (accs -> regs);
//            other group gates its PREVIOUS-phase accs + writes h.
// Gate work is data-independent of same-phase MFMA work -> intra-wave
// interleave; serial chain per phase = max(read+MFMA, gates) not sum.
// 60 phases of half work, one barrier each; single-buffered planes
// (write -> barrier -> read next phase). Edges run branch-free: garbage
// accs gated into a scrap plane, c-writebacks predicated (NaN-safe select).
// Weights pre-scaled (i/f/o rows by -log2e, g by +2log2e) -> bare exp2;
// gate math = 7 trans/h (common-denominator c-update, fused sig*tanh).

typedef _Float16 half8 __attribute__((ext_vector_type(8)));
typedef float floatx4 __attribute__((ext_vector_type(4)));

#define NFRAG 112
#define WS_BIAS_OFF (NFRAG * 1024)
#define K2 2.8853900817779268f      // 2*log2(e)

#if __has_builtin(__builtin_amdgcn_exp2f)
#define EXP2(v) __builtin_amdgcn_exp2f(v)
#else
#define EXP2(v) __expf(0.6931471805599453f * (v))
#endif
#define RCP(v) __builtin_amdgcn_rcpf(v)

__global__ void prep_kernel(const float* __restrict__ Wih0, const float* __restrict__ Whh0,
                            const float* __restrict__ bih0, const float* __restrict__ bhh0,
                            const float* __restrict__ Wih1, const float* __restrict__ Whh1,
                            const float* __restrict__ bih1, const float* __restrict__ bhh1,
                            _Float16* __restrict__ wA, float* __restrict__ wBias) {
    int idx = blockIdx.x * blockDim.x + threadIdx.x;
    if (idx < NFRAG * 512) {
        int f = idx >> 9, slot = idx & 511;
        int lane = slot >> 3, j = slot & 7;
        int mt, kt, layer;
        if (f < 48) { layer = 0; mt = f / 3; kt = f % 3; }
        else        { layer = 1; int f2 = f - 48; mt = f2 >> 2; kt = f2 & 3; }
        int m = mt * 16 + (lane & 15);
        int k = kt * 32 + (lane >> 4) * 8 + j;
        int u = m >> 2, g = m & 3;
        int row = g * 64 + u;
        float v;
        if (layer == 0) {
            if (k < 28)       v = Wih0[row * 28 + k];
            else if (k == 28) v = bih0[row] + bhh0[row];
            else if (k < 32)  v = 0.f;
            else              v = Whh0[row * 64 + (k - 32)];
        } else {
            if (k < 64)       v = Wih1[row * 64 + k];
            else              v = Whh1[row * 64 + (k - 64)];
        }
        float s = (g == 2) ? K2 : -1.4426950408889634f;
        wA[idx] = (_Float16)(v * s);
    } else if (idx < NFRAG * 512 + 256) {
        int m = idx - NFRAG * 512;
        int g = m & 3;
        int row = g * 64 + (m >> 2);
        float s = (g == 2) ? K2 : -1.4426950408889634f;
        wBias[m] = (bih1[row] + bhh1[row]) * s;
    }
}

// Breadth-first gate batch on PRE-SCALED accs, with keep-predicated c update.
// cn = [c*pg*pi + (eg-1)*pf] / (pf*pg*pi)  (1 rcp); h = (ec-1)/(ec*po+po).
template <int N>
__device__ __forceinline__ void gate_batch(const floatx4* acc, float* c, const bool* keep,
                                           _Float16* const* planes, const int* offs) {
    float ei[N], ef[N], eg[N], eo[N];
    #pragma unroll
    for (int i = 0; i < N; ++i) {
        floatx4 a = acc[i];
        ei[i] = EXP2(a[0]);
        ef[i] = EXP2(a[1]);
        eg[i] = EXP2(a[2]);
        eo[i] = EXP2(a[3]);
    }
    float num[N], rd[N], po[N];
    #pragma unroll
    for (int i = 0; i < N; ++i) {
        float pi = 1.0f + ei[i];
        float pf = 1.0f + ef[i];
        float pg = 1.0f + eg[i];
        po[i] = 1.0f + eo[i];
        float m = pg * pi;
        num[i] = c[i] * m + (eg[i] - 1.0f) * pf;
        rd[i]  = RCP(pf * m);
    }
    float ec[N];
    #pragma unroll
    for (int i = 0; i < N; ++i) {
        float cn = num[i] * rd[i];
        c[i] = keep[i] ? cn : 0.0f;      // NaN-safe: select, not multiply
        ec[i] = EXP2(K2 * cn);
    }
    #pragma unroll
    for (int i = 0; i < N; ++i) {
        float r2 = RCP(ec[i] * po[i] + po[i]);
        planes[i][offs[i]] = (_Float16)((ec[i] - 1.0f) * r2);
    }
}

__launch_bounds__(512, 4)
__global__ void lstm_mfma(const float* __restrict__ x,
                          const _Float16* __restrict__ wA,
                          const float* __restrict__ wBias,
                          const float* __restrict__ Wlin, const float* __restrict__ blin,
                          float* __restrict__ out) {
    __shared__ __align__(16) _Float16 h0p[2][1024];   // [group][frag-linear]
    __shared__ __align__(16) _Float16 h1p[2][1024];
    __shared__ __align__(16) _Float16 xb[2][512];
    __shared__ __align__(16) _Float16 scrap[1024];    // edge-phase write sink
    __shared__ float wlin_s[640];
    __shared__ float blin_s[10];

    const int lane = threadIdx.x;
    const int w    = threadIdx.y;      // 0..7
    const int tid  = w * 64 + lane;
    const int quad = lane >> 4;
    const int col  = lane & 15;

    // ---- A fragments: wave owns m-tiles MT = 2w+j ----
    half8 A0[2][3], A1[2][4];
    floatx4 bias1[2];
    int hwr[2];
    #pragma unroll
    for (int j = 0; j < 2; ++j) {
        const int MT = 2 * w + j;
        #pragma unroll
        for (int kt = 0; kt < 3; ++kt)
            A0[j][kt] = *(const half8*)(wA + (MT * 3 + kt) * 512 + lane * 8);
        #pragma unroll
        for (int kt = 0; kt < 4; ++kt)
            A1[j][kt] = *(const half8*)(wA + (48 + MT * 4 + kt) * 512 + lane * 8);
        const int u = MT * 4 + quad;
        bias1[j] = *(const floatx4*)(wBias + u * 4);
        hwr[j] = (u >> 5) * 512 + (((u >> 3) & 3) * 16 + col) * 8 + (u & 7);
    }

    const int xrd = lane * 8;
    const int hrd0 = lane * 8;
    const int hrd1 = 512 + lane * 8;

    // ---- x staging: thread covers (col_s = tid>>5, k_s = tid&31) ----
    const int ks = tid & 31;
    const int cs = tid >> 5;           // 0..15
    const bool xvalid = ks < 28;
    const bool xone   = (ks == 28);
    int xoff[2];
    #pragma unroll
    for (int g = 0; g < 2; ++g)
        xoff[g] = (blockIdx.x * 32 + g * 16 + cs) * 784 + ks;
    const int xstg = ((ks >> 3) * 16 + cs) * 8 + (ks & 7);

    // ---- prologue: zero h planes, stage x(0) for both groups ----
    {
        ((int*)h0p)[tid] = 0; ((int*)h0p)[tid + 512] = 0;
        ((int*)h1p)[tid] = 0; ((int*)h1p)[tid + 512] = 0;
        float v0 = xvalid ? x[xoff[0]] : 0.f;
        float v1 = xvalid ? x[xoff[1]] : 0.f;
        xb[0][xstg] = xone ? (_Float16)1.0f : (_Float16)v0;
        xb[1][xstg] = xone ? (_Float16)1.0f : (_Float16)v1;
    }
    __syncthreads();

    // carried per-group accs (gated one phase after being built) + c-state
    floatx4 acc0g[2][2], acc1g[2][2];
    #pragma unroll
    for (int g = 0; g < 2; ++g)
        #pragma unroll
        for (int j = 0; j < 2; ++j) {
            acc0g[g][j] = (floatx4){0.f, 0.f, 0.f, 0.f};
            acc1g[g][j] = (floatx4){0.f, 0.f, 0.f, 0.f};
        }
    float c0[2][2] = {{0.f, 0.f}, {0.f, 0.f}};
    float c1[2][2] = {{0.f, 0.f}, {0.f, 0.f}};

// One phase: group GM does reads+MFMAs (building acc*g[GM]); group GG gates
// its carried accs at activation PGATE and writes h + stages next x.
#define PHASE_BODY(GM, GG, PGATE)                                                   \
    {                                                                               \
        const int pg_ = (PGATE);                                                    \
        const int tt_ = (pg_ + 2 < 27) ? (pg_ + 2) : 27;                            \
        float xv_ = xvalid ? x[xoff[GG] + tt_ * 28] : 0.f;                          \
        half8 bx_ = *(const half8*)&xb[GM][xrd];                                    \
        half8 bh0_0 = *(const half8*)&h0p[GM][hrd0];                                \
        half8 bh0_1 = *(const half8*)&h0p[GM][hrd1];                                \
        half8 bh1_0 = *(const half8*)&h1p[GM][hrd0];                                \
        half8 bh1_1 = *(const half8*)&h1p[GM][hrd1];                                \
        /* gates for GG (independent of this phase's MFMAs) */                      \
        {                                                                           \
            _Float16* d0 = (pg_ < 27) ? &h0p[GG][0] : scrap;                        \
            _Float16* d1 = (pg_ >= 0) ? &h1p[GG][0] : scrap;                        \
            const bool k0 = (pg_ >= -1), k1 = (pg_ >= 0);                           \
            floatx4 a4[4] = {acc0g[GG][0], acc0g[GG][1], acc1g[GG][0], acc1g[GG][1]};\
            float   cc[4] = {c0[GG][0], c0[GG][1], c1[GG][0], c1[GG][1]};           \
            bool    kk[4] = {k0, k0, k1, k1};                                       \
            _Float16* pl[4] = {d0, d0, d1, d1};                                     \
            int     of[4] = {hwr[0], hwr[1], hwr[0], hwr[1]};                       \
            gate_batch<4>(a4, cc, kk, pl, of);                                      \
            c0[GG][0] = cc[0]; c0[GG][1] = cc[1];                                   \
            c1[GG][0] = cc[2]; c1[GG][1] = cc[3];                                   \
        }                                                                           \
        /* MFMAs for GM */                                                          \
        _Pragma("unroll")                                                           \
        for (int j = 0; j < 2; ++j) {                                               \
            floatx4 a = __builtin_amdgcn_mfma_f32_16x16x32_f16(                     \
                            A0[j][0], bx_, (floatx4){0.f, 0.f, 0.f, 0.f}, 0, 0, 0); \
            a = __builtin_amdgcn_mfma_f32_16x16x32_f16(A0[j][1], bh0_0, a, 0, 0, 0);\
            a = __builtin_amdgcn_mfma_f32_16x16x32_f16(A0[j][2], bh0_1, a, 0, 0, 0);\
            acc0g[GM][j] = a;                                                       \
            floatx4 b = bias1[j];                                                   \
            b = __builtin_amdgcn_mfma_f32_16x16x32_f16(A1[j][0], bh0_0, b, 0, 0, 0);\
            b = __builtin_amdgcn_mfma_f32_16x16x32_f16(A1[j][1], bh0_1, b, 0, 0, 0);\
            b = __builtin_amdgcn_mfma_f32_16x16x32_f16(A1[j][2], bh1_0, b, 0, 0, 0);\
            b = __builtin_amdgcn_mfma_f32_16x16x32_f16(A1[j][3], bh1_1, b, 0, 0, 0);\
            acc1g[GM][j] = b;                                                       \
        }                                                                           \
        xb[GG][xstg] = xone ? (_Float16)1.0f : (_Float16)xv_;                       \
        __syncthreads();                                                            \
    }

    for (int i = 0; i <= 28; ++i) {
        PHASE_BODY(0, 1, i - 2)     // even phase: A MFMAs (pm=i-1), B gates (pg=i-2)
        PHASE_BODY(1, 0, i - 1)     // odd phase:  B MFMAs (pm=i-1), A gates (pg=i-1)
    }

    // final phase: group B gates pg=27 -> writes h1_B(27)
    {
        _Float16* d1 = &h1p[1][0];
        floatx4 a4[4] = {acc0g[1][0], acc0g[1][1], acc1g[1][0], acc1g[1][1]};
        float   cc[4] = {c0[1][0], c0[1][1], c1[1][0], c1[1][1]};
        bool    kk[4] = {false, false, true, true};
        _Float16* pl[4] = {scrap, scrap, d1, d1};
        int     of[4] = {hwr[0], hwr[1], hwr[0], hwr[1]};
        gate_batch<4>(a4, cc, kk, pl, of);
    }
    __syncthreads();

    // ---- epilogue: out = h1(27) @ Wlin^T + blin ----
    wlin_s[tid] = Wlin[tid];
    if (tid < 128) wlin_s[512 + tid] = Wlin[512 + tid];
    if (tid < 10)  blin_s[tid] = blin[tid];
    __syncthreads();
    if (tid < 320) {
        int b = tid / 10, o = tid - b * 10;
        int G = b >> 4, bl = b & 15;
        float a = blin_s[o];
        #pragma unroll 8
        for (int uu = 0; uu < 64; ++uu) {
            float hv = (float)h1p[G][(uu >> 5) * 512 + (((uu >> 3) & 3) * 16 + bl) * 8 + (uu & 7)];
            a += wlin_s[o * 64 + uu] * hv;
        }
        out[(blockIdx.x * 32 + b) * 10 + o] = a;
    }
}

extern "C" void kernel_launch(void* const* d_in, const int* in_sizes, int n_in,
                              void* d_out, int out_size, void* d_ws, size_t ws_size,
                              hipStream_t stream) {
    const float* x    = (const float*)d_in[0];
    const float* Wih0 = (const float*)d_in[1];
    const float* Whh0 = (const float*)d_in[2];
    const float* bih0 = (const float*)d_in[3];
    const float* bhh0 = (const float*)d_in[4];
    const float* Wih1 = (const float*)d_in[5];
    const float* Whh1 = (const float*)d_in[6];
    const float* bih1 = (const float*)d_in[7];
    const float* bhh1 = (const float*)d_in[8];
    const float* Wlin = (const float*)d_in[9];
    const float* blin = (const float*)d_in[10];
    float* out = (float*)d_out;

    _Float16* wA    = (_Float16*)d_ws;
    float*    wBias = (float*)((char*)d_ws + WS_BIAS_OFF);

    prep_kernel<<<225, 256, 0, stream>>>(Wih0, Whh0, bih0, bhh0,
                                         Wih1, Whh1, bih1, bhh1, wA, wBias);
    lstm_mfma<<<512, dim3(64, 8), 0, stream>>>(x, wA, wBias, Wlin, blin, out);
}

// Round 4
// 171.714 us; speedup vs baseline: 1.0460x; 1.0460x over previous
//
#include <hip/hip_runtime.h>

// --- MFMA fp16 LSTM, Round 15: r12 (known-good) + half-phase block stagger ---
// r12 (95.7us, 29 phases): 512-thr blocks, 2/CU. Per-CU-phase budget:
// LDS ~3.0k cyc (160 b128 reads + scattered u16 writes + 587 conflict-cyc),
// VALU+trans ~2.8k/SIMD, MFMA ~0.5k, barrier ~0.7k; measured 7.9k = SUM of
// pipes -> near-zero overlap (barrier releases all 16 waves at once; they
// burst on LDS together, then trans together).
// r13 (105us): group-split halved work/phase but doubled barriers. REVERTED.
// r14: paired-rcp overflowed f32 at legal extreme preacts -> FAILED. SCRAPPED
// (also cost-model wash: 1 trans saved vs ~3 VALU added on shared issue BW).
// r15: ONLY change vs r12 = blocks with bit8 set sleep ~3.8k cyc (half phase)
// before the loop. Under round-robin dispatch, blocks b and b+256 co-reside
// on a CU; offset blocks interleave LDS-burst vs trans-burst -> phase ->
// max(pipes) instead of sum. Timing-only change: correctness unaffected.
// Phase p: layer1(t=p) reads h0(p),h1(p-1); layer0(t=p+1) reads x(p+1),h0(p);
// 29 barriers. Weights pre-scaled (i/f/o by -log2e, g by +2log2e) -> bare
// exp2. Gate math = r12's verified 7-trans form (per-element rcp, no clamp).
// B planes frag-linear (lane reads 16B at lane*16, conflict-free b128).

typedef _Float16 half8 __attribute__((ext_vector_type(8)));
typedef float floatx4 __attribute__((ext_vector_type(4)));

#define NFRAG 112
#define WS_BIAS_OFF (NFRAG * 1024)
#define K2 2.8853900817779268f      // 2*log2(e)

#if __has_builtin(__builtin_amdgcn_exp2f)
#define EXP2(v) __builtin_amdgcn_exp2f(v)
#else
#define EXP2(v) __expf(0.6931471805599453f * (v))
#endif
#define RCP(v) __builtin_amdgcn_rcpf(v)

__global__ void prep_kernel(const float* __restrict__ Wih0, const float* __restrict__ Whh0,
                            const float* __restrict__ bih0, const float* __restrict__ bhh0,
                            const float* __restrict__ Wih1, const float* __restrict__ Whh1,
                            const float* __restrict__ bih1, const float* __restrict__ bhh1,
                            _Float16* __restrict__ wA, float* __restrict__ wBias) {
    int idx = blockIdx.x * blockDim.x + threadIdx.x;
    if (idx < NFRAG * 512) {
        int f = idx >> 9, slot = idx & 511;
        int lane = slot >> 3, j = slot & 7;
        int mt, kt, layer;
        if (f < 48) { layer = 0; mt = f / 3; kt = f % 3; }
        else        { layer = 1; int f2 = f - 48; mt = f2 >> 2; kt = f2 & 3; }
        int m = mt * 16 + (lane & 15);
        int k = kt * 32 + (lane >> 4) * 8 + j;
        int u = m >> 2, g = m & 3;
        int row = g * 64 + u;
        float v;
        if (layer == 0) {
            if (k < 28)       v = Wih0[row * 28 + k];
            else if (k == 28) v = bih0[row] + bhh0[row];
            else if (k < 32)  v = 0.f;
            else              v = Whh0[row * 64 + (k - 32)];
        } else {
            if (k < 64)       v = Wih1[row * 64 + k];
            else              v = Whh1[row * 64 + (k - 64)];
        }
        float s = (g == 2) ? K2 : -1.4426950408889634f;
        wA[idx] = (_Float16)(v * s);
    } else if (idx < NFRAG * 512 + 256) {
        int m = idx - NFRAG * 512;
        int g = m & 3;
        int row = g * 64 + (m >> 2);
        float s = (g == 2) ? K2 : -1.4426950408889634f;
        wBias[m] = (bih1[row] + bhh1[row]) * s;
    }
}

// Breadth-first N-tile gate batch on PRE-SCALED accs (r12 verified form).
// cn = [c*pg*pi + (eg-1)*pf] / (pf*pg*pi)  (1 rcp); h = (ec-1)/(ec*po+po).
template <int N>
__device__ __forceinline__ void gate_batch(const floatx4* acc, float* c,
                                           _Float16* const* planes, const int* offs) {
    float ei[N], ef[N], eg[N], eo[N];
    #pragma unroll
    for (int i = 0; i < N; ++i) {
        floatx4 a = acc[i];
        ei[i] = EXP2(a[0]);
        ef[i] = EXP2(a[1]);
        eg[i] = EXP2(a[2]);
        eo[i] = EXP2(a[3]);
    }
    float num[N], rd[N], po[N];
    #pragma unroll
    for (int i = 0; i < N; ++i) {
        float pi = 1.0f + ei[i];
        float pf = 1.0f + ef[i];
        float pg = 1.0f + eg[i];
        po[i] = 1.0f + eo[i];
        float m = pg * pi;
        num[i] = c[i] * m + (eg[i] - 1.0f) * pf;
        rd[i]  = RCP(pf * m);
    }
    float ec[N];
    #pragma unroll
    for (int i = 0; i < N; ++i) {
        float cn = num[i] * rd[i];
        c[i] = cn;
        ec[i] = EXP2(K2 * cn);
    }
    #pragma unroll
    for (int i = 0; i < N; ++i) {
        float r2 = RCP(ec[i] * po[i] + po[i]);
        planes[i][offs[i]] = (_Float16)((ec[i] - 1.0f) * r2);
    }
}

__launch_bounds__(512, 4)
__global__ void lstm_mfma(const float* __restrict__ x,
                          const _Float16* __restrict__ wA,
                          const float* __restrict__ wBias,
                          const float* __restrict__ Wlin, const float* __restrict__ blin,
                          float* __restrict__ out) {
    __shared__ __align__(16) _Float16 h0p[2][2048];  // [parity][frag-linear]
    __shared__ __align__(16) _Float16 h1p[2][2048];
    __shared__ __align__(16) _Float16 xb[2][1024];
    __shared__ float wlin_s[640];
    __shared__ float blin_s[10];

    const int lane = threadIdx.x;
    const int w    = threadIdx.y;      // 0..7
    const int tid  = w * 64 + lane;
    const int quad = lane >> 4;
    const int col  = lane & 15;

    // ---- A fragments: wave owns m-tiles MT = 2w+j, units u = MT*4+quad ----
    half8 A0[2][3], A1[2][4];
    floatx4 bias1[2];
    int hwr[2][2];
    #pragma unroll
    for (int j = 0; j < 2; ++j) {
        const int MT = 2 * w + j;
        #pragma unroll
        for (int kt = 0; kt < 3; ++kt)
            A0[j][kt] = *(const half8*)(wA + (MT * 3 + kt) * 512 + lane * 8);
        #pragma unroll
        for (int kt = 0; kt < 4; ++kt)
            A1[j][kt] = *(const half8*)(wA + (48 + MT * 4 + kt) * 512 + lane * 8);
        const int u = MT * 4 + quad;
        bias1[j] = *(const floatx4*)(wBias + u * 4);
        #pragma unroll
        for (int in = 0; in < 2; ++in)
            hwr[j][in] = (in * 2 + (u >> 5)) * 512 + (((u >> 3) & 3) * 16 + col) * 8 + (u & 7);
    }

    // ---- t-invariant LDS read offsets ----
    int xrd[2], hrd[2][2];
    #pragma unroll
    for (int in = 0; in < 2; ++in) {
        xrd[in] = in * 512 + lane * 8;
        #pragma unroll
        for (int kt = 0; kt < 2; ++kt) hrd[kt][in] = (in * 2 + kt) * 512 + lane * 8;
    }

    // ---- x staging: thread covers b=tid>>5 and b+16, i=tid&31 ----
    const int xi = tid & 31;
    const bool xvalid = xi < 28;
    const int xbi = tid >> 5;          // 0..15
    const float* xg = x + (blockIdx.x * 32 + xbi) * 784 + xi;
    const int xstg = ((xi >> 3) * 16 + xbi) * 8 + (xi & 7);   // in=0; +512 for in=1

    // ---- init: zero h(-1) planes, stage x(0) ----
    {
        ((int*)&h0p[1][0])[tid * 2 + 0] = 0;
        ((int*)&h0p[1][0])[tid * 2 + 1] = 0;
        ((int*)&h1p[1][0])[tid * 2 + 0] = 0;
        ((int*)&h1p[1][0])[tid * 2 + 1] = 0;
        float xv0 = xvalid ? xg[0] : 0.f;
        float xv1 = xvalid ? xg[16 * 784] : 0.f;
        xb[0][xstg]       = (xi == 28) ? (_Float16)1.0f : (_Float16)xv0;
        xb[0][xstg + 512] = (xi == 28) ? (_Float16)1.0f : (_Float16)xv1;
    }
    __syncthreads();

    // ---- forced inter-block stagger: assumed CU pairing (b, b+256) ----
    // Timing-only: blocks share no state, so this cannot affect results.
    if ((blockIdx.x >> 8) & 1) {
        #pragma unroll
        for (int s = 0; s < 4; ++s) __builtin_amdgcn_s_sleep(15);  // ~3.8k cyc
    }

    float c0[2][2] = {{0.f, 0.f}, {0.f, 0.f}};
    float c1[2][2] = {{0.f, 0.f}, {0.f, 0.f}};

    for (int p = -1; p <= 27; ++p) {
        const int pr  = p & 1;
        const int pr1 = pr ^ 1;
        const bool doL0 = (p < 27);
        const bool doL1 = (p >= 0);

        // (1) global prefetch x(p+2)
        float xn0 = 0.f, xn1 = 0.f;
        if (p <= 25 && xvalid) {
            xn0 = xg[(p + 2) * 28];
            xn1 = xg[16 * 784 + (p + 2) * 28];
        }

        // (2) up-front B-frag reads: bx + bh0 (6 b128)
        half8 bx[2], bh0[2][2];
        if (doL0) {
            #pragma unroll
            for (int in = 0; in < 2; ++in)
                bx[in] = *(const half8*)&xb[pr1][xrd[in]];
        }
        #pragma unroll
        for (int kt = 0; kt < 2; ++kt)
            #pragma unroll
            for (int in = 0; in < 2; ++in)
                bh0[kt][in] = *(const half8*)&h0p[pr][hrd[kt][in]];

        // (3) L0 MFMAs + L1 h0-part MFMAs (consume bx, bh0)
        floatx4 acc0[2][2], acc1[2][2];
        if (doL0) {
            #pragma unroll
            for (int j = 0; j < 2; ++j)
                #pragma unroll
                for (int in = 0; in < 2; ++in) {
                    acc0[j][in] = __builtin_amdgcn_mfma_f32_16x16x32_f16(
                                      A0[j][0], bx[in], (floatx4){0.f, 0.f, 0.f, 0.f}, 0, 0, 0);
                    #pragma unroll
                    for (int kt = 0; kt < 2; ++kt)
                        acc0[j][in] = __builtin_amdgcn_mfma_f32_16x16x32_f16(
                                          A0[j][kt + 1], bh0[kt][in], acc0[j][in], 0, 0, 0);
                }
        }
        if (doL1) {
            #pragma unroll
            for (int j = 0; j < 2; ++j)
                #pragma unroll
                for (int in = 0; in < 2; ++in) {
                    acc1[j][in] = bias1[j];
                    #pragma unroll
                    for (int kt = 0; kt < 2; ++kt)
                        acc1[j][in] = __builtin_amdgcn_mfma_f32_16x16x32_f16(
                                          A1[j][kt], bh0[kt][in], acc1[j][in], 0, 0, 0);
                }

            // (4) bh1 reads then L1 tail MFMAs
            half8 bh1[2][2];
            #pragma unroll
            for (int kt = 0; kt < 2; ++kt)
                #pragma unroll
                for (int in = 0; in < 2; ++in)
                    bh1[kt][in] = *(const half8*)&h1p[pr1][hrd[kt][in]];
            #pragma unroll
            for (int j = 0; j < 2; ++j)
                #pragma unroll
                for (int kt = 0; kt < 2; ++kt)
                    #pragma unroll
                    for (int in = 0; in < 2; ++in)
                        acc1[j][in] = __builtin_amdgcn_mfma_f32_16x16x32_f16(
                                          A1[j][kt + 2], bh1[kt][in], acc1[j][in], 0, 0, 0);
        }

        // (5) gates: one merged breadth-first batch
        if (doL0 && doL1) {
            floatx4 a8[8] = {acc0[0][0], acc0[0][1], acc0[1][0], acc0[1][1],
                             acc1[0][0], acc1[0][1], acc1[1][0], acc1[1][1]};
            float   cc[8] = {c0[0][0], c0[0][1], c0[1][0], c0[1][1],
                             c1[0][0], c1[0][1], c1[1][0], c1[1][1]};
            _Float16* pl[8] = {h0p[pr1], h0p[pr1], h0p[pr1], h0p[pr1],
                               h1p[pr],  h1p[pr],  h1p[pr],  h1p[pr]};
            int offs[8] = {hwr[0][0], hwr[0][1], hwr[1][0], hwr[1][1],
                           hwr[0][0], hwr[0][1], hwr[1][0], hwr[1][1]};
            gate_batch<8>(a8, cc, pl, offs);
            c0[0][0] = cc[0]; c0[0][1] = cc[1]; c0[1][0] = cc[2]; c0[1][1] = cc[3];
            c1[0][0] = cc[4]; c1[0][1] = cc[5]; c1[1][0] = cc[6]; c1[1][1] = cc[7];
        } else if (doL0) {
            floatx4 a4[4] = {acc0[0][0], acc0[0][1], acc0[1][0], acc0[1][1]};
            float   cc[4] = {c0[0][0], c0[0][1], c0[1][0], c0[1][1]};
            _Float16* pl[4] = {h0p[pr1], h0p[pr1], h0p[pr1], h0p[pr1]};
            int offs[4] = {hwr[0][0], hwr[0][1], hwr[1][0], hwr[1][1]};
            gate_batch<4>(a4, cc, pl, offs);
            c0[0][0] = cc[0]; c0[0][1] = cc[1]; c0[1][0] = cc[2]; c0[1][1] = cc[3];
        } else {
            floatx4 a4[4] = {acc1[0][0], acc1[0][1], acc1[1][0], acc1[1][1]};
            float   cc[4] = {c1[0][0], c1[0][1], c1[1][0], c1[1][1]};
            _Float16* pl[4] = {h1p[pr], h1p[pr], h1p[pr], h1p[pr]};
            int offs[4] = {hwr[0][0], hwr[0][1], hwr[1][0], hwr[1][1]};
            gate_batch<4>(a4, cc, pl, offs);
            c1[0][0] = cc[0]; c1[0][1] = cc[1]; c1[1][0] = cc[2]; c1[1][1] = cc[3];
        }

        // (6) x staging, then barrier
        if (p <= 25) {
            xb[pr][xstg]       = (xi == 28) ? (_Float16)1.0f : (_Float16)xn0;
            xb[pr][xstg + 512] = (xi == 28) ? (_Float16)1.0f : (_Float16)xn1;
        }
        __syncthreads();
    }

    // ---- epilogue: out = h1(27) @ Wlin^T + blin ----
    wlin_s[tid] = Wlin[tid];
    if (tid < 128) wlin_s[512 + tid] = Wlin[512 + tid];
    if (tid < 10)  blin_s[tid] = blin[tid];
    __syncthreads();
    if (tid < 320) {
        int b = tid / 10, o = tid - b * 10;
        float a = blin_s[o];
        #pragma unroll 8
        for (int uu = 0; uu < 64; ++uu) {
            float hv = (float)h1p[1][((b >> 4) * 2 + (uu >> 5)) * 512 + (((uu >> 3) & 3) * 16 + (b & 15)) * 8 + (uu & 7)];
            a += wlin_s[o * 64 + uu] * hv;
        }
        out[(blockIdx.x * 32 + b) * 10 + o] = a;
    }
}

extern "C" void kernel_launch(void* const* d_in, const int* in_sizes, int n_in,
                              void* d_out, int out_size, void* d_ws, size_t ws_size,
                              hipStream_t stream) {
    const float* x    = (const float*)d_in[0];
    const float* Wih0 = (const float*)d_in[1];
    const float* Whh0 = (const float*)d_in[2];
    const float* bih0 = (const float*)d_in[3];
    const float* bhh0 = (const float*)d_in[4];
    const float* Wih1 = (const float*)d_in[5];
    const float* Whh1 = (const float*)d_in[6];
    const float* bih1 = (const float*)d_in[7];
    const float* bhh1 = (const float*)d_in[8];
    const float* Wlin = (const float*)d_in[9];
    const float* blin = (const float*)d_in[10];
    float* out = (float*)d_out;

    _Float16* wA    = (_Float16*)d_ws;
    float*    wBias = (float*)((char*)d_ws + WS_BIAS_OFF);

    prep_kernel<<<225, 256, 0, stream>>>(Wih0, Whh0, bih0, bhh0,
                                         Wih1, Whh1, bih1, bhh1, wA, wBias);
    lstm_mfma<<<512, dim3(64, 8), 0, stream>>>(x, wA, wBias, Wlin, blin, out);
}